// Round 7
// baseline (417.201 us; speedup 1.0000x reference)
//
#include <hip/hip_runtime.h>
#include <hip/hip_bf16.h>

// MPNN fused pipeline, bf16 MFMA (16x16x32), fp32 accum.
// R7 changes vs R6 (R6 kept 2 blocks/CU because grid=512 == 2x256CU; the
// 32-row tile's extra barriers with unchanged occupancy made it regress):
//  - js=4 -> grid 128x2x4 = 1024 blocks = 4/CU; regs (~148) allow 3
//    resident, LDS (40KB) allows 4 -> 12 waves/CU + 1 queued block.
//  - H = 2304 (R2-style duplicated-Wout reduction of 4 partials/sim).
//  - XCD swizzle for z=4: each (sim,jz) combo pinned to one XCD -> its
//    e (4MB) + Xt j-slice (1MB) resident in that XCD's L2.
// Counter model: SQ_LDS_BANK_CONFLICT ~ b128 count (inherent ~12cyc/b128);
// expect ~unchanged 18.9M while dur drops.

typedef short bf16x8  __attribute__((ext_vector_type(8)));
typedef short short4v __attribute__((ext_vector_type(4)));
typedef float f32x4   __attribute__((ext_vector_type(4)));

__device__ inline short f2bf(float x) {                // fp32 -> bf16 RNE
    unsigned u = __builtin_bit_cast(unsigned, x);
    return (short)((u + 0x7fffu + ((u >> 16) & 1u)) >> 16);
}

__device__ inline void cp16_async(const short* g, short* l) {
    __builtin_amdgcn_global_load_lds(
        (const __attribute__((address_space(1))) unsigned int*)g,
        (__attribute__((address_space(3))) unsigned int*)l, 16, 0, 0);
}

// ---------------------------------------------------------------- prep_x
__global__ void prep_x(const float* __restrict__ X, short* __restrict__ h,
                       int ldh, short* __restrict__ Xt)
{
    __shared__ short tile[32][33];
    const int r0 = blockIdx.x * 32, c0 = blockIdx.y * 32;
    const int tx = threadIdx.x, ty = threadIdx.y;      // 32 x 8
    #pragma unroll
    for (int i = 0; i < 4; ++i) {
        int row = ty + i * 8;
        short b = f2bf(X[(size_t)(r0 + row) * 256 + c0 + tx]);
        tile[row][tx] = b;
        h[(size_t)(r0 + row) * ldh + c0 + tx] = b;
    }
    __syncthreads();
    #pragma unroll
    for (int i = 0; i < 4; ++i) {
        int row = ty + i * 8;
        Xt[(size_t)(c0 + row) * 8192 + r0 + tx] = tile[tx][row];
    }
}

// -------------------------------------------------------------- prep_w_all
__global__ void prep_w_all(const float* __restrict__ W1,
                           const float* __restrict__ W2,
                           const float* __restrict__ Wo,
                           short* __restrict__ Wt1, short* __restrict__ Wt2,
                           short* __restrict__ Wto, int H, int js)
{
    const int z = blockIdx.z;
    const float* src; short* dst; int ldwt, k_off;
    if (z == 0)      { src = W1; dst = Wt1; ldwt = 256; k_off = 0; }
    else if (z == 1) { src = W2; dst = Wt2; ldwt = 256; k_off = 0; }
    else {
        int g = z - 2;                         // 0 .. 2*js
        int srcrow = (g == 0) ? 0 : (g <= js ? 256 : 512);
        src = Wo + (size_t)srcrow * 256; dst = Wto; ldwt = H; k_off = g * 256;
    }
    __shared__ short tile[32][33];
    const int k0 = blockIdx.x * 32, n0 = blockIdx.y * 32;
    const int tx = threadIdx.x, ty = threadIdx.y;
    #pragma unroll
    for (int i = 0; i < 4; ++i) {
        int row = ty + i * 8;
        tile[row][tx] = f2bf(src[(size_t)(k0 + row) * 256 + n0 + tx]);
    }
    __syncthreads();
    #pragma unroll
    for (int i = 0; i < 4; ++i) {
        int row = ty + i * 8;
        dst[(size_t)(n0 + row) * ldwt + k_off + k0 + tx] = tile[tx][row];
    }
}

// -------------------------------------------------------- gemm_bias_relu
__global__ __launch_bounds__(256, 1)
void gemm_bias_relu(const short* __restrict__ A, int lda,
                    const short* __restrict__ Bt0, const short* __restrict__ Bt1,
                    int K,
                    const float* __restrict__ bias0, const float* __restrict__ bias1,
                    void* __restrict__ out0, void* __restrict__ out1,
                    int out_bf16, int ldo, int swz)
{
    const short* Bt   = blockIdx.z ? Bt1   : Bt0;
    const float* bias = blockIdx.z ? bias1 : bias0;
    void*        outp = blockIdx.z ? out1  : out0;

    const int m0 = blockIdx.x * 64, n0 = blockIdx.y * 64;
    const int t = threadIdx.x;
    const int w = t >> 6, l = t & 63, lr = l & 15, q = l >> 4;

    __shared__ __attribute__((aligned(16))) short As[64 * 64];
    __shared__ __attribute__((aligned(16))) short Bs[64 * 64];

    f32x4 acc[4];
    #pragma unroll
    for (int i = 0; i < 4; ++i) acc[i] = f32x4{0.f, 0.f, 0.f, 0.f};

    for (int k0 = 0; k0 < K; k0 += 64) {
        __syncthreads();
        for (int i = t; i < 64 * 8; i += 256) {
            int row = i >> 3, g = i & 7;
            *(int4*)&As[row * 64 + ((g ^ (row & 7)) << 3)] =
                *(const int4*)(A + (size_t)(m0 + row) * lda + k0 + g * 8);
            *(int4*)&Bs[row * 64 + ((g ^ (row & 7)) << 3)] =
                *(const int4*)(Bt + (size_t)(n0 + row) * K + k0 + g * 8);
        }
        __syncthreads();
        #pragma unroll
        for (int ks = 0; ks < 2; ++ks) {
            int arow = w * 16 + lr;
            bf16x8 af = *(const bf16x8*)&As[arow * 64 + (((ks*4 + q) ^ (arow & 7)) << 3)];
            #pragma unroll
            for (int nt = 0; nt < 4; ++nt) {
                int brow = nt * 16 + lr;
                bf16x8 bfg = *(const bf16x8*)&Bs[brow * 64 + (((ks*4 + q) ^ (brow & 7)) << 3)];
                acc[nt] = __builtin_amdgcn_mfma_f32_16x16x32_bf16(af, bfg, acc[nt], 0, 0, 0);
            }
        }
    }
    #pragma unroll
    for (int nt = 0; nt < 4; ++nt)
        #pragma unroll
        for (int r = 0; r < 4; ++r) {
            int m = m0 + w * 16 + q * 4 + r;      // C/D: row = quad*4 + reg
            int n = n0 + nt * 16 + lr;            //      col = lane & 15
            float v = acc[nt][r] + bias[n];
            v = v > 0.f ? v : 0.f;
            if (out_bf16) {
                int col = swz ? ((((n >> 3) ^ (m & 7)) << 3) | (n & 7)) : n;
                ((short*)outp)[(size_t)m * ldo + col] = f2bf(v);
            } else {
                ((float*)outp)[(size_t)m * ldo + n] = v;
            }
        }
}

// ---------------------------------------------------------- fused_simagg
// j-tile = 32 rows; Ks/Ps double-buffered; one barrier per tile; 40KB LDS.
__global__ __launch_bounds__(256, 3)
void fused_simagg(const short* __restrict__ e1, const short* __restrict__ e2,
                  const short* __restrict__ Xt, short* __restrict__ h,
                  int ldh, int tiles_per_split)
{
    // XCD swizzle (dispatch round-robins linear id % 8 across XCDs):
    int sim, jz, mx;
    if (gridDim.x == 128 && gridDim.z == 4) {
        // 1024 blocks: pin each (sim,jz) combo to one XCD.
        int flat = blockIdx.x + 128 * (blockIdx.y + 2 * blockIdx.z);
        int xcd = flat & 7, slot = flat >> 3;
        sim = xcd >> 2; jz = xcd & 3; mx = slot;
    } else if (gridDim.x == 128 && gridDim.z == 2) {
        // 512 blocks: each (sim,jz) quadrant on 2 fixed XCDs.
        int flat = blockIdx.x + 128 * (blockIdx.y + 2 * blockIdx.z);
        int xcd = flat & 7, slot = flat >> 3;
        int quad = xcd >> 1;
        sim = quad >> 1; jz = quad & 1;
        mx = slot + (xcd & 1) * 64;
    } else { sim = blockIdx.y; jz = blockIdx.z; mx = blockIdx.x; }

    const short* e = sim ? e2 : e1;
    const int m0 = mx * 64;
    const int t = threadIdx.x;
    const int w = t >> 6, l = t & 63, lr = l & 15, q = l >> 4;
    const int mh = (w & 1) * 32;               // m-half of this wave
    const int jq = (w >> 1) * 16;              // j-half (16 rows) of the tile

    __shared__ __attribute__((aligned(16))) short Ks[2][32 * 256]; // 32 KB
    __shared__ __attribute__((aligned(16))) short Ps[2][64 * 32];  //  8 KB

    // Q frags: rows m0 + mh + ms*16 + lr
    bf16x8 qf[2][8];
    #pragma unroll
    for (int ms = 0; ms < 2; ++ms) {
        const int mrow = m0 + mh + ms * 16 + lr;
        const short* qrow = e + (size_t)mrow * 256;
        #pragma unroll
        for (int kc = 0; kc < 8; ++kc)
            qf[ms][kc] = *(const bf16x8*)(qrow + (((kc * 4 + q) ^ (mrow & 7)) << 3));
    }

    f32x4 agg[16];
    #pragma unroll
    for (int i = 0; i < 16; ++i) agg[i] = f32x4{0.f, 0.f, 0.f, 0.f};

    const int jbase = jz * tiles_per_split;
    const int wub = t & ~63;                   // wave-uniform thread base

    // prologue: stage tile 0 (16 KB) into Ks[0]
    {
        const short* src = e + (size_t)(jbase * 32) * 256;
        #pragma unroll
        for (int it = 0; it < 4; ++it)
            cp16_async(src + (size_t)(it * 256 + t) * 8,
                       &Ks[0][(size_t)(it * 256 + wub) * 8]);
    }
    __syncthreads();

    for (int jt = 0; jt < tiles_per_split; ++jt) {
        const int cur = jt & 1, nxt = cur ^ 1;
        const int j0 = (jbase + jt) * 32;

        // async prefetch of next K tile (drains at the barrier)
        if (jt + 1 < tiles_per_split) {
            const short* src = e + (size_t)(j0 + 32) * 256;
            #pragma unroll
            for (int it = 0; it < 4; ++it)
                cp16_async(src + (size_t)(it * 256 + t) * 8,
                           &Ks[nxt][(size_t)(it * 256 + wub) * 8]);
        }

        // vf register prefetch (B-frag of V, K=32 = whole tile)
        bf16x8 vfr[4];
        #pragma unroll
        for (int nt = 0; nt < 4; ++nt) {
            int n = w * 64 + nt * 16 + lr;
            vfr[nt] = *(const bf16x8*)(Xt + (size_t)n * 8192 + j0 + q * 8);
        }

        // S^T quadrant: wave reads only its 16 K-rows (jq .. jq+15)
        const short* Kb = &Ks[cur][0];
        f32x4 s[2];
        s[0] = f32x4{0.f, 0.f, 0.f, 0.f};
        s[1] = f32x4{0.f, 0.f, 0.f, 0.f};
        #pragma unroll
        for (int kc = 0; kc < 8; ++kc) {
            int row = jq + lr;
            bf16x8 kf = *(const bf16x8*)&Kb[row * 256 + (((kc*4 + q) ^ (row & 7)) << 3)];
            #pragma unroll
            for (int ms = 0; ms < 2; ++ms)
                s[ms] = __builtin_amdgcn_mfma_f32_16x16x32_bf16(
                    kf, qf[ms][kc], s[ms], 0, 0, 0);
        }

        // P scatter: 4 consecutive j at fixed m -> one aligned b64 each
        #pragma unroll
        for (int ms = 0; ms < 2; ++ms) {
            int mloc = mh + ms * 16 + lr;
            int jj = jq + q * 4;
            int off = mloc * 32 + (((jj >> 3) ^ (mloc & 3)) << 3) + (jj & 7);
            short4v pk = { f2bf(s[ms][0] * (1.0f/256.0f)),
                           f2bf(s[ms][1] * (1.0f/256.0f)),
                           f2bf(s[ms][2] * (1.0f/256.0f)),
                           f2bf(s[ms][3] * (1.0f/256.0f)) };
            *(short4v*)&Ps[cur][off] = pk;
        }
        __syncthreads();   // the ONLY barrier per tile

        // agg += P V : single K=32 step; pf streamed (1 live frag), vf regs
        #pragma unroll
        for (int mt = 0; mt < 4; ++mt) {
            int row = mt * 16 + lr;
            bf16x8 pf = *(const bf16x8*)&Ps[cur][row * 32 + ((q ^ (row & 3)) << 3)];
            #pragma unroll
            for (int nt = 0; nt < 4; ++nt)
                agg[mt * 4 + nt] = __builtin_amdgcn_mfma_f32_16x16x32_bf16(
                    pf, vfr[nt], agg[mt * 4 + nt], 0, 0, 0);
        }
    }

    const int colbase = 256 + (sim * gridDim.z + jz) * 256;
    #pragma unroll
    for (int mt = 0; mt < 4; ++mt)
        #pragma unroll
        for (int nt = 0; nt < 4; ++nt)
            #pragma unroll
            for (int r = 0; r < 4; ++r) {
                int m = m0 + mt * 16 + q * 4 + r;
                int n = w * 64 + nt * 16 + lr;
                h[(size_t)m * ldh + colbase + n] = f2bf(agg[mt * 4 + nt][r]);
            }
}

// ---------------------------------------------------------------- launch
extern "C" void kernel_launch(void* const* d_in, const int* in_sizes, int n_in,
                              void* d_out, int out_size, void* d_ws, size_t ws_size,
                              hipStream_t stream)
{
    const float* edge_x = (const float*)d_in[0];
    const float* W1 = (const float*)d_in[1];
    const float* b1 = (const float*)d_in[2];
    const float* W2 = (const float*)d_in[3];
    const float* b2 = (const float*)d_in[4];
    const float* Wo = (const float*)d_in[5];
    const float* bo = (const float*)d_in[6];

    const size_t need4 = (size_t)8192*2304*2 + 4194304u*3 + 131072u*2 + (size_t)2304*256*2;
    const size_t need2 = (size_t)8192*1280*2 + 4194304u*3 + 131072u*2 + (size_t)1280*256*2;
    const int js = (ws_size >= need4) ? 4 : (ws_size >= need2) ? 2 : 1;
    const int H = 256 + 2 * js * 256;              // 2304 / 1280 / 768

    char* ws = (char*)d_ws;
    short* h   = (short*)ws;
    short* Xt  = (short*)(ws + (size_t)8192 * H * 2);
    short* e1  = (short*)((char*)Xt + 4194304);
    short* e2  = (short*)((char*)e1 + 4194304);
    short* Wt1 = (short*)((char*)e2 + 4194304);
    short* Wt2 = (short*)((char*)Wt1 + 131072);
    short* Wto = (short*)((char*)Wt2 + 131072);

    prep_x<<<dim3(256, 8), dim3(32, 8), 0, stream>>>(edge_x, h, H, Xt);
    prep_w_all<<<dim3(8, 8, 3 + 2 * js), dim3(32, 8), 0, stream>>>(
        W1, W2, Wo, Wt1, Wt2, Wto, H, js);

    // e1 and e2 GEMMs in one dispatch (grid.z)
    gemm_bias_relu<<<dim3(128, 4, 2), 256, 0, stream>>>(
        h, H, Wt1, Wt2, 256, b1, b2, e1, e2, 1, 256, 1);
    // j-tiles of 32 rows: 256 total, split js ways
    fused_simagg<<<dim3(128, 2, js), 256, 0, stream>>>(e1, e2, Xt, h, H, 256 / js);
    gemm_bias_relu<<<dim3(128, 4, 1), 256, 0, stream>>>(
        h, H, Wto, Wto, H, bo, bo, (float*)d_out, (float*)d_out, 0, 256, 0);
}

// Round 8
// 267.240 us; speedup vs baseline: 1.5611x; 1.5611x over previous
//
#include <hip/hip_runtime.h>
#include <hip/hip_bf16.h>

// MPNN fused pipeline, bf16 MFMA (16x16x32), fp32 accum.
// R8: producer/consumer wave specialization in fused_simagg.
// WHY: rounds 4-7 proved occupancy is capped by the VGPR bracket
// (waves/SIMD steps at total regs 64/128/256, m68/m69; VGPR_Count counter
// excludes AGPRs). Monolithic waves need qf(64)+agg(64)+... ~150 regs ->
// 2 waves/SIMD forever. Split: QK waves hold qf only, PV waves hold agg
// only; disjoint branches share physical regs -> kernel fits <=128 ->
// 4 waves/SIMD = 16 waves/CU (2x R4's residency).
//   block = 512 thr: waves 0-3 QK (S^T=K.Q^T -> Ps), waves 4-7 PV
//   (Ps x V -> agg), PV lags QK by 1 tile via Ps dbuf; 1 barrier/tile.
//   64-row j-tile (best LDS economics: kf amp=2), Ks dbuf DMA staging,
//   LDS 80KB = 2 blocks/CU, js=2, quadrant XCD pinning.

typedef short bf16x8  __attribute__((ext_vector_type(8)));
typedef short short4v __attribute__((ext_vector_type(4)));
typedef float f32x4   __attribute__((ext_vector_type(4)));

__device__ inline short f2bf(float x) {                // fp32 -> bf16 RNE
    unsigned u = __builtin_bit_cast(unsigned, x);
    return (short)((u + 0x7fffu + ((u >> 16) & 1u)) >> 16);
}

__device__ inline void cp16_async(const short* g, short* l) {
    __builtin_amdgcn_global_load_lds(
        (const __attribute__((address_space(1))) unsigned int*)g,
        (__attribute__((address_space(3))) unsigned int*)l, 16, 0, 0);
}

// ---------------------------------------------------------------- prep_x
__global__ void prep_x(const float* __restrict__ X, short* __restrict__ h,
                       int ldh, short* __restrict__ Xt)
{
    __shared__ short tile[32][33];
    const int r0 = blockIdx.x * 32, c0 = blockIdx.y * 32;
    const int tx = threadIdx.x, ty = threadIdx.y;      // 32 x 8
    #pragma unroll
    for (int i = 0; i < 4; ++i) {
        int row = ty + i * 8;
        short b = f2bf(X[(size_t)(r0 + row) * 256 + c0 + tx]);
        tile[row][tx] = b;
        h[(size_t)(r0 + row) * ldh + c0 + tx] = b;
    }
    __syncthreads();
    #pragma unroll
    for (int i = 0; i < 4; ++i) {
        int row = ty + i * 8;
        Xt[(size_t)(c0 + row) * 8192 + r0 + tx] = tile[tx][row];
    }
}

// -------------------------------------------------------------- prep_w_all
__global__ void prep_w_all(const float* __restrict__ W1,
                           const float* __restrict__ W2,
                           const float* __restrict__ Wo,
                           short* __restrict__ Wt1, short* __restrict__ Wt2,
                           short* __restrict__ Wto, int H, int js)
{
    const int z = blockIdx.z;
    const float* src; short* dst; int ldwt, k_off;
    if (z == 0)      { src = W1; dst = Wt1; ldwt = 256; k_off = 0; }
    else if (z == 1) { src = W2; dst = Wt2; ldwt = 256; k_off = 0; }
    else {
        int g = z - 2;                         // 0 .. 2*js
        int srcrow = (g == 0) ? 0 : (g <= js ? 256 : 512);
        src = Wo + (size_t)srcrow * 256; dst = Wto; ldwt = H; k_off = g * 256;
    }
    __shared__ short tile[32][33];
    const int k0 = blockIdx.x * 32, n0 = blockIdx.y * 32;
    const int tx = threadIdx.x, ty = threadIdx.y;
    #pragma unroll
    for (int i = 0; i < 4; ++i) {
        int row = ty + i * 8;
        tile[row][tx] = f2bf(src[(size_t)(k0 + row) * 256 + n0 + tx]);
    }
    __syncthreads();
    #pragma unroll
    for (int i = 0; i < 4; ++i) {
        int row = ty + i * 8;
        dst[(size_t)(n0 + row) * ldwt + k_off + k0 + tx] = tile[tx][row];
    }
}

// -------------------------------------------------------- gemm_bias_relu
__global__ __launch_bounds__(256, 1)
void gemm_bias_relu(const short* __restrict__ A, int lda,
                    const short* __restrict__ Bt0, const short* __restrict__ Bt1,
                    int K,
                    const float* __restrict__ bias0, const float* __restrict__ bias1,
                    void* __restrict__ out0, void* __restrict__ out1,
                    int out_bf16, int ldo, int swz)
{
    const short* Bt   = blockIdx.z ? Bt1   : Bt0;
    const float* bias = blockIdx.z ? bias1 : bias0;
    void*        outp = blockIdx.z ? out1  : out0;

    const int m0 = blockIdx.x * 64, n0 = blockIdx.y * 64;
    const int t = threadIdx.x;
    const int w = t >> 6, l = t & 63, lr = l & 15, q = l >> 4;

    __shared__ __attribute__((aligned(16))) short As[64 * 64];
    __shared__ __attribute__((aligned(16))) short Bs[64 * 64];

    f32x4 acc[4];
    #pragma unroll
    for (int i = 0; i < 4; ++i) acc[i] = f32x4{0.f, 0.f, 0.f, 0.f};

    for (int k0 = 0; k0 < K; k0 += 64) {
        __syncthreads();
        for (int i = t; i < 64 * 8; i += 256) {
            int row = i >> 3, g = i & 7;
            *(int4*)&As[row * 64 + ((g ^ (row & 7)) << 3)] =
                *(const int4*)(A + (size_t)(m0 + row) * lda + k0 + g * 8);
            *(int4*)&Bs[row * 64 + ((g ^ (row & 7)) << 3)] =
                *(const int4*)(Bt + (size_t)(n0 + row) * K + k0 + g * 8);
        }
        __syncthreads();
        #pragma unroll
        for (int ks = 0; ks < 2; ++ks) {
            int arow = w * 16 + lr;
            bf16x8 af = *(const bf16x8*)&As[arow * 64 + (((ks*4 + q) ^ (arow & 7)) << 3)];
            #pragma unroll
            for (int nt = 0; nt < 4; ++nt) {
                int brow = nt * 16 + lr;
                bf16x8 bfg = *(const bf16x8*)&Bs[brow * 64 + (((ks*4 + q) ^ (brow & 7)) << 3)];
                acc[nt] = __builtin_amdgcn_mfma_f32_16x16x32_bf16(af, bfg, acc[nt], 0, 0, 0);
            }
        }
    }
    #pragma unroll
    for (int nt = 0; nt < 4; ++nt)
        #pragma unroll
        for (int r = 0; r < 4; ++r) {
            int m = m0 + w * 16 + q * 4 + r;      // C/D: row = quad*4 + reg
            int n = n0 + nt * 16 + lr;            //      col = lane & 15
            float v = acc[nt][r] + bias[n];
            v = v > 0.f ? v : 0.f;
            if (out_bf16) {
                int col = swz ? ((((n >> 3) ^ (m & 7)) << 3) | (n & 7)) : n;
                ((short*)outp)[(size_t)m * ldo + col] = f2bf(v);
            } else {
                ((float*)outp)[(size_t)m * ldo + n] = v;
            }
        }
}

// ---------------------------------------------------------- fused_simagg
// 512 threads: waves 0-3 produce P(jt) into Ps[jt&1]; waves 4-7 consume
// P(jt-1) from Ps[(jt-1)&1] with V from Xt. One barrier per tile.
__global__ __launch_bounds__(512, 4)
void fused_simagg(const short* __restrict__ e1, const short* __restrict__ e2,
                  const short* __restrict__ Xt, short* __restrict__ h,
                  int ldh, int tiles_per_split)
{
    // XCD swizzle: grid (128,2,2) -> each (sim,jz) quadrant on 2 fixed XCDs.
    int sim, jz, mx;
    if (gridDim.x == 128 && gridDim.z == 2) {
        int flat = blockIdx.x + 128 * (blockIdx.y + 2 * blockIdx.z);
        int xcd = flat & 7, slot = flat >> 3;
        int quad = xcd >> 1;
        sim = quad >> 1; jz = quad & 1;
        mx = slot + (xcd & 1) * 64;
    } else { sim = blockIdx.y; jz = blockIdx.z; mx = blockIdx.x; }

    const short* e = sim ? e2 : e1;
    const int m0 = mx * 64;
    const int t = threadIdx.x;
    const int w = t >> 6, l = t & 63, lr = l & 15, q = l >> 4;

    __shared__ __attribute__((aligned(16))) short Ks[2][64 * 256]; // 64 KB
    __shared__ __attribute__((aligned(16))) short Ps[2][64 * 64];  // 16 KB

    const int jbase = jz * tiles_per_split;
    const int T = tiles_per_split;

    if (w < 4) {
        // ===================== producer: S^T = K.Q^T -> Ps =====================
        const int mh = (w & 1) * 32;           // m-half of this wave
        const int jh = (w >> 1) * 32;          // j-half of this wave
        const int wub = t & ~63;               // wave-uniform base (t in 0..255)

        bf16x8 qf[2][8];                       // 64 VGPRs: Q rows, unswizzled
        #pragma unroll
        for (int ms = 0; ms < 2; ++ms) {
            const int mrow = m0 + mh + ms * 16 + lr;
            const short* qrow = e + (size_t)mrow * 256;
            #pragma unroll
            for (int kc = 0; kc < 8; ++kc)
                qf[ms][kc] = *(const bf16x8*)(qrow + (((kc * 4 + q) ^ (mrow & 7)) << 3));
        }
        // prologue: stage tile 0 (32 KB, 8 chunks per thread over 256 thr)
        {
            const short* src = e + (size_t)(jbase * 64) * 256;
            #pragma unroll
            for (int it = 0; it < 8; ++it)
                cp16_async(src + (size_t)(it * 256 + t) * 8,
                           &Ks[0][(size_t)(it * 256 + wub) * 8]);
        }
        __syncthreads();                       // barrier 0 (matches consumer)

        for (int jt = 0; jt <= T; ++jt) {
            if (jt < T) {
                const int cur = jt & 1;
                const int j0 = (jbase + jt) * 64;
                if (jt + 1 < T) {              // async prefetch of next K tile
                    const short* src = e + (size_t)(j0 + 64) * 256;
                    #pragma unroll
                    for (int it = 0; it < 8; ++it)
                        cp16_async(src + (size_t)(it * 256 + t) * 8,
                                   &Ks[cur ^ 1][(size_t)(it * 256 + wub) * 8]);
                }
                // S^T quadrant: read only this wave's 32 K-rows
                const short* Kb = &Ks[cur][0];
                f32x4 s[2][2];                 // [js2][ms]
                #pragma unroll
                for (int a = 0; a < 2; ++a)
                    #pragma unroll
                    for (int b = 0; b < 2; ++b) s[a][b] = f32x4{0.f, 0.f, 0.f, 0.f};
                #pragma unroll
                for (int kc = 0; kc < 8; ++kc) {
                    #pragma unroll
                    for (int js2 = 0; js2 < 2; ++js2) {
                        int row = jh + js2 * 16 + lr;
                        bf16x8 kf = *(const bf16x8*)&Kb[row * 256 + (((kc*4 + q) ^ (row & 7)) << 3)];
                        #pragma unroll
                        for (int ms = 0; ms < 2; ++ms)
                            s[js2][ms] = __builtin_amdgcn_mfma_f32_16x16x32_bf16(
                                kf, qf[ms][kc], s[js2][ms], 0, 0, 0);
                    }
                }
                // P scatter: 4 consecutive j at fixed m -> one aligned b64
                #pragma unroll
                for (int js2 = 0; js2 < 2; ++js2)
                    #pragma unroll
                    for (int ms = 0; ms < 2; ++ms) {
                        int mloc = mh + ms * 16 + lr;
                        int jj = jh + js2 * 16 + q * 4;
                        int off = mloc * 64 + (((jj >> 3) ^ (mloc & 7)) << 3) + (jj & 7);
                        short4v pk = { f2bf(s[js2][ms][0] * (1.0f/256.0f)),
                                       f2bf(s[js2][ms][1] * (1.0f/256.0f)),
                                       f2bf(s[js2][ms][2] * (1.0f/256.0f)),
                                       f2bf(s[js2][ms][3] * (1.0f/256.0f)) };
                        *(short4v*)&Ps[cur][off] = pk;
                    }
            }
            __syncthreads();                   // barrier per tile
        }
    } else {
        // ===================== consumer: agg += P(jt-1) x V =====================
        const int wv = w - 4;                  // n-strip selector 0..3
        f32x4 agg[16];                         // 64 AGPRs
        #pragma unroll
        for (int i = 0; i < 16; ++i) agg[i] = f32x4{0.f, 0.f, 0.f, 0.f};

        __syncthreads();                       // barrier 0 (matches producer)

        for (int jt = 0; jt <= T; ++jt) {
            if (jt >= 1) {
                const int p = (jt - 1) & 1;
                const int j0 = (jbase + jt - 1) * 64;
                #pragma unroll
                for (int ks = 0; ks < 2; ++ks) {
                    bf16x8 pf[4], vfr[4];
                    #pragma unroll
                    for (int nt = 0; nt < 4; ++nt) {
                        int n = wv * 64 + nt * 16 + lr;
                        vfr[nt] = *(const bf16x8*)(Xt + (size_t)n * 8192 + j0 + (ks * 4 + q) * 8);
                    }
                    #pragma unroll
                    for (int mt = 0; mt < 4; ++mt) {
                        int row = mt * 16 + lr;
                        pf[mt] = *(const bf16x8*)&Ps[p][row * 64 + (((ks*4 + q) ^ (row & 7)) << 3)];
                    }
                    #pragma unroll
                    for (int nt = 0; nt < 4; ++nt)
                        #pragma unroll
                        for (int mt = 0; mt < 4; ++mt)
                            agg[mt * 4 + nt] = __builtin_amdgcn_mfma_f32_16x16x32_bf16(
                                pf[mt], vfr[nt], agg[mt * 4 + nt], 0, 0, 0);
                }
            }
            __syncthreads();                   // barrier per tile
        }

        const int colbase = 256 + (sim * gridDim.z + jz) * 256;
        #pragma unroll
        for (int mt = 0; mt < 4; ++mt)
            #pragma unroll
            for (int nt = 0; nt < 4; ++nt)
                #pragma unroll
                for (int r = 0; r < 4; ++r) {
                    int m = m0 + mt * 16 + q * 4 + r;
                    int n = wv * 64 + nt * 16 + lr;
                    h[(size_t)m * ldh + colbase + n] = f2bf(agg[mt * 4 + nt][r]);
                }
    }
}

// ---------------------------------------------------------------- launch
extern "C" void kernel_launch(void* const* d_in, const int* in_sizes, int n_in,
                              void* d_out, int out_size, void* d_ws, size_t ws_size,
                              hipStream_t stream)
{
    const float* edge_x = (const float*)d_in[0];
    const float* W1 = (const float*)d_in[1];
    const float* b1 = (const float*)d_in[2];
    const float* W2 = (const float*)d_in[3];
    const float* b2 = (const float*)d_in[4];
    const float* Wo = (const float*)d_in[5];
    const float* bo = (const float*)d_in[6];

    const size_t need2 = (size_t)8192*1280*2 + 4194304u*3 + 131072u*2 + (size_t)1280*256*2;
    const int js = (ws_size >= need2) ? 2 : 1;
    const int H = 256 + 2 * js * 256;              // 1280 or 768

    char* ws = (char*)d_ws;
    short* h   = (short*)ws;
    short* Xt  = (short*)(ws + (size_t)8192 * H * 2);
    short* e1  = (short*)((char*)Xt + 4194304);
    short* e2  = (short*)((char*)e1 + 4194304);
    short* Wt1 = (short*)((char*)e2 + 4194304);
    short* Wt2 = (short*)((char*)Wt1 + 131072);
    short* Wto = (short*)((char*)Wt2 + 131072);

    prep_x<<<dim3(256, 8), dim3(32, 8), 0, stream>>>(edge_x, h, H, Xt);
    prep_w_all<<<dim3(8, 8, 3 + 2 * js), dim3(32, 8), 0, stream>>>(
        W1, W2, Wo, Wt1, Wt2, Wto, H, js);

    // e1 and e2 GEMMs in one dispatch (grid.z)
    gemm_bias_relu<<<dim3(128, 4, 2), 256, 0, stream>>>(
        h, H, Wt1, Wt2, 256, b1, b2, e1, e2, 1, 256, 1);
    // 64-row j-tiles: (8192/64)/js per split
    fused_simagg<<<dim3(128, 2, js), 512, 0, stream>>>(e1, e2, Xt, h, H, 128 / js);
    gemm_bias_relu<<<dim3(128, 4, 1), 256, 0, stream>>>(
        h, H, Wto, Wto, H, bo, bo, (float*)d_out, (float*)d_out, 0, 256, 0);
}

// Round 9
// 248.129 us; speedup vs baseline: 1.6814x; 1.0770x over previous
//
#include <hip/hip_runtime.h>
#include <hip/hip_bf16.h>

// MPNN fused pipeline. R9 = R8 (producer/consumer wave specialization,
// 43% occ, fused 173us) + fp8-e4m3 QK producer path:
//  - e1/e2 get an fp8 shadow (e_to_fp8 kernel, 8B-granule swizzled layout
//    shared by global DMA image and LDS frag reads).
//  - producer: Ks staging 32->16KB/tile (DMA drain halves), kf = ds_read_b64,
//    qf 64->32 VGPRs, mfma_f32_16x16x32_fp8_fp8 (bf16 rate; memory-only win).
//  - consumer BYTE-IDENTICAL to R8 (it sits at exactly 128 regs = the
//    4-waves/SIMD bracket edge; R5 taught us what happens past it).
//  - prep_x + prep_w merged into one launch (offsets e_to_fp8 launch).

typedef short bf16x8  __attribute__((ext_vector_type(8)));
typedef short short4v __attribute__((ext_vector_type(4)));
typedef float f32x4   __attribute__((ext_vector_type(4)));

__device__ inline short f2bf(float x) {                // fp32 -> bf16 RNE
    unsigned u = __builtin_bit_cast(unsigned, x);
    return (short)((u + 0x7fffu + ((u >> 16) & 1u)) >> 16);
}
__device__ inline float bf2f(short b) {
    return __builtin_bit_cast(float, (unsigned)((unsigned short)b) << 16);
}
__device__ inline void cp16_async(const char* g, char* l) {
    __builtin_amdgcn_global_load_lds(
        (const __attribute__((address_space(1))) unsigned int*)g,
        (__attribute__((address_space(3))) unsigned int*)l, 16, 0, 0);
}

// ------------------------------------------------------------------ prep_all
// All blocks: edge_x fp32 -> bf16 h[:,0:256] + Xt [256][8192].
// Blocks (x<8,y<8) additionally loop the weight transposes.
__global__ void prep_all(const float* __restrict__ X, short* __restrict__ h,
                         int ldh, short* __restrict__ Xt,
                         const float* __restrict__ W1, const float* __restrict__ W2,
                         const float* __restrict__ Wo,
                         short* __restrict__ Wt1, short* __restrict__ Wt2,
                         short* __restrict__ Wto, int H, int js)
{
    __shared__ short tile[32][33];
    const int tx = threadIdx.x, ty = threadIdx.y;      // 32 x 8
    {
        const int r0 = blockIdx.x * 32, c0 = blockIdx.y * 32;
        #pragma unroll
        for (int i = 0; i < 4; ++i) {
            int row = ty + i * 8;
            short b = f2bf(X[(size_t)(r0 + row) * 256 + c0 + tx]);
            tile[row][tx] = b;
            h[(size_t)(r0 + row) * ldh + c0 + tx] = b;
        }
        __syncthreads();
        #pragma unroll
        for (int i = 0; i < 4; ++i) {
            int row = ty + i * 8;
            Xt[(size_t)(c0 + row) * 8192 + r0 + tx] = tile[tx][row];
        }
    }
    if (blockIdx.x < 8 && blockIdx.y < 8) {
        const int k0 = blockIdx.x * 32, n0 = blockIdx.y * 32;
        for (int z = 0; z < 3 + 2 * js; ++z) {
            const float* src; short* dst; int ldwt, k_off;
            if (z == 0)      { src = W1; dst = Wt1; ldwt = 256; k_off = 0; }
            else if (z == 1) { src = W2; dst = Wt2; ldwt = 256; k_off = 0; }
            else {
                int g = z - 2;
                int srcrow = (g == 0) ? 0 : (g <= js ? 256 : 512);
                src = Wo + (size_t)srcrow * 256; dst = Wto; ldwt = H; k_off = g * 256;
            }
            __syncthreads();
            #pragma unroll
            for (int i = 0; i < 4; ++i) {
                int row = ty + i * 8;
                tile[row][tx] = f2bf(src[(size_t)(k0 + row) * 256 + n0 + tx]);
            }
            __syncthreads();
            #pragma unroll
            for (int i = 0; i < 4; ++i) {
                int row = ty + i * 8;
                dst[(size_t)(n0 + row) * ldwt + k_off + k0 + tx] = tile[tx][row];
            }
        }
    }
}

// -------------------------------------------------------- gemm_bias_relu
__global__ __launch_bounds__(256, 1)
void gemm_bias_relu(const short* __restrict__ A, int lda,
                    const short* __restrict__ Bt0, const short* __restrict__ Bt1,
                    int K,
                    const float* __restrict__ bias0, const float* __restrict__ bias1,
                    void* __restrict__ out0, void* __restrict__ out1,
                    int out_bf16, int ldo, int swz)
{
    const short* Bt   = blockIdx.z ? Bt1   : Bt0;
    const float* bias = blockIdx.z ? bias1 : bias0;
    void*        outp = blockIdx.z ? out1  : out0;

    const int m0 = blockIdx.x * 64, n0 = blockIdx.y * 64;
    const int t = threadIdx.x;
    const int w = t >> 6, l = t & 63, lr = l & 15, q = l >> 4;

    __shared__ __attribute__((aligned(16))) short As[64 * 64];
    __shared__ __attribute__((aligned(16))) short Bs[64 * 64];

    f32x4 acc[4];
    #pragma unroll
    for (int i = 0; i < 4; ++i) acc[i] = f32x4{0.f, 0.f, 0.f, 0.f};

    for (int k0 = 0; k0 < K; k0 += 64) {
        __syncthreads();
        for (int i = t; i < 64 * 8; i += 256) {
            int row = i >> 3, g = i & 7;
            *(int4*)&As[row * 64 + ((g ^ (row & 7)) << 3)] =
                *(const int4*)(A + (size_t)(m0 + row) * lda + k0 + g * 8);
            *(int4*)&Bs[row * 64 + ((g ^ (row & 7)) << 3)] =
                *(const int4*)(Bt + (size_t)(n0 + row) * K + k0 + g * 8);
        }
        __syncthreads();
        #pragma unroll
        for (int ks = 0; ks < 2; ++ks) {
            int arow = w * 16 + lr;
            bf16x8 af = *(const bf16x8*)&As[arow * 64 + (((ks*4 + q) ^ (arow & 7)) << 3)];
            #pragma unroll
            for (int nt = 0; nt < 4; ++nt) {
                int brow = nt * 16 + lr;
                bf16x8 bfg = *(const bf16x8*)&Bs[brow * 64 + (((ks*4 + q) ^ (brow & 7)) << 3)];
                acc[nt] = __builtin_amdgcn_mfma_f32_16x16x32_bf16(af, bfg, acc[nt], 0, 0, 0);
            }
        }
    }
    #pragma unroll
    for (int nt = 0; nt < 4; ++nt)
        #pragma unroll
        for (int r = 0; r < 4; ++r) {
            int m = m0 + w * 16 + q * 4 + r;      // C/D: row = quad*4 + reg
            int n = n0 + nt * 16 + lr;            //      col = lane & 15
            float v = acc[nt][r] + bias[n];
            v = v > 0.f ? v : 0.f;
            if (out_bf16) {
                int col = swz ? ((((n >> 3) ^ (m & 7)) << 3) | (n & 7)) : n;
                ((short*)outp)[(size_t)m * ldo + col] = f2bf(v);
            } else {
                ((float*)outp)[(size_t)m * ldo + n] = v;
            }
        }
}

// ------------------------------------------------------------- e_to_fp8
// bf16 e (16B-chunk swizzled) -> fp8 e4m3 shadow, 8B-granule swizzled:
// granule g of row m lands at slot (g&24)|((g&7)^(m&7)). One thread per 8B.
__global__ void e_to_fp8(const short* __restrict__ e1, const short* __restrict__ e2,
                         char* __restrict__ o1, char* __restrict__ o2)
{
    int gid = blockIdx.x * 256 + threadIdx.x;          // 0 .. 524287
    const short* e = (gid >> 18) ? e2 : e1;
    char*        o = (gid >> 18) ? o2 : o1;
    int rem = gid & 262143;
    int m = rem >> 5, g = rem & 31;
    int slot = (g & 24) | ((g & 7) ^ (m & 7));
    bf16x8 v = *(const bf16x8*)(e + (size_t)m * 256 + slot * 8);
    float f[8];
    #pragma unroll
    for (int i = 0; i < 8; ++i) f[i] = bf2f(v[i]);
    int a = __builtin_amdgcn_cvt_pk_fp8_f32(f[0], f[1], 0, false);
    a     = __builtin_amdgcn_cvt_pk_fp8_f32(f[2], f[3], a, true);
    int b = __builtin_amdgcn_cvt_pk_fp8_f32(f[4], f[5], 0, false);
    b     = __builtin_amdgcn_cvt_pk_fp8_f32(f[6], f[7], b, true);
    int2 r{a, b};
    *(int2*)(o + (size_t)m * 256 + slot * 8) = r;
}

// ---------------------------------------------------------- fused_simagg
// 512 thr: waves 0-3 produce P(jt) (fp8 QK) into Ps[jt&1]; waves 4-7
// consume P(jt-1) with V from Xt (bf16, unchanged from R8). 1 barrier/tile.
__global__ __launch_bounds__(512, 4)
void fused_simagg(const char* __restrict__ e1f8, const char* __restrict__ e2f8,
                  const short* __restrict__ Xt, short* __restrict__ h,
                  int ldh, int tiles_per_split)
{
    // XCD swizzle: grid (128,2,2) -> each (sim,jz) quadrant on 2 fixed XCDs.
    int sim, jz, mx;
    if (gridDim.x == 128 && gridDim.z == 2) {
        int flat = blockIdx.x + 128 * (blockIdx.y + 2 * blockIdx.z);
        int xcd = flat & 7, slot = flat >> 3;
        int quad = xcd >> 1;
        sim = quad >> 1; jz = quad & 1;
        mx = slot + (xcd & 1) * 64;
    } else { sim = blockIdx.y; jz = blockIdx.z; mx = blockIdx.x; }

    const char* e8 = sim ? e2f8 : e1f8;
    const int m0 = mx * 64;
    const int t = threadIdx.x;
    const int w = t >> 6, l = t & 63, lr = l & 15, q = l >> 4;

    __shared__ __attribute__((aligned(16))) char  Ks8[2][64 * 256]; // 32 KB
    __shared__ __attribute__((aligned(16))) short Ps[2][64 * 64];   // 16 KB

    const int jbase = jz * tiles_per_split;
    const int T = tiles_per_split;

    if (w < 4) {
        // ============ producer: S^T = K.Q^T (fp8) -> Ps (bf16) ============
        const int mh = (w & 1) * 32;           // m-half of this wave
        const int jh = (w >> 1) * 32;          // j-half of this wave
        const int wub = t & ~63;               // wave-uniform base (t 0..255)

        long qf8[2][8];                        // 32 VGPRs: fp8 Q frags
        #pragma unroll
        for (int ms = 0; ms < 2; ++ms) {
            const int mrow = m0 + mh + ms * 16 + lr;
            const char* qrow = e8 + (size_t)mrow * 256;
            #pragma unroll
            for (int kc = 0; kc < 8; ++kc) {
                int g = kc * 4 + q;
                int slot = (g & 24) | ((g & 7) ^ (mrow & 7));
                qf8[ms][kc] = *(const long*)(qrow + slot * 8);
            }
        }
        // prologue: stage tile 0 (16 KB = 1024 chunks over 256 threads)
        {
            const char* src = e8 + (size_t)(jbase * 64) * 256;
            #pragma unroll
            for (int it = 0; it < 4; ++it)
                cp16_async(src + (size_t)(it * 256 + t) * 16,
                           &Ks8[0][(size_t)(it * 256 + wub) * 16]);
        }
        __syncthreads();                       // barrier 0 (matches consumer)

        for (int jt = 0; jt <= T; ++jt) {
            if (jt < T) {
                const int cur = jt & 1;
                const int j0 = (jbase + jt) * 64;
                if (jt + 1 < T) {              // async prefetch of next K tile
                    const char* src = e8 + (size_t)(j0 + 64) * 256;
                    #pragma unroll
                    for (int it = 0; it < 4; ++it)
                        cp16_async(src + (size_t)(it * 256 + t) * 16,
                                   &Ks8[cur ^ 1][(size_t)(it * 256 + wub) * 16]);
                }
                const char* Kb = &Ks8[cur][0];
                f32x4 s[2][2];                 // [js2][ms]
                #pragma unroll
                for (int a = 0; a < 2; ++a)
                    #pragma unroll
                    for (int b = 0; b < 2; ++b) s[a][b] = f32x4{0.f, 0.f, 0.f, 0.f};
                #pragma unroll
                for (int kc = 0; kc < 8; ++kc) {
                    #pragma unroll
                    for (int js2 = 0; js2 < 2; ++js2) {
                        int row = jh + js2 * 16 + lr;
                        int g = kc * 4 + q;
                        int slot = (g & 24) | ((g & 7) ^ (row & 7));
                        long kf = *(const long*)&Kb[row * 256 + slot * 8];
                        #pragma unroll
                        for (int ms = 0; ms < 2; ++ms)
                            s[js2][ms] = __builtin_amdgcn_mfma_f32_16x16x32_fp8_fp8(
                                kf, qf8[ms][kc], s[js2][ms], 0, 0, 0);
                    }
                }
                // P scatter: 4 consecutive j at fixed m -> one aligned b64
                #pragma unroll
                for (int js2 = 0; js2 < 2; ++js2)
                    #pragma unroll
                    for (int ms = 0; ms < 2; ++ms) {
                        int mloc = mh + ms * 16 + lr;
                        int jj = jh + js2 * 16 + q * 4;
                        int off = mloc * 64 + (((jj >> 3) ^ (mloc & 7)) << 3) + (jj & 7);
                        short4v pk = { f2bf(s[js2][ms][0] * (1.0f/256.0f)),
                                       f2bf(s[js2][ms][1] * (1.0f/256.0f)),
                                       f2bf(s[js2][ms][2] * (1.0f/256.0f)),
                                       f2bf(s[js2][ms][3] * (1.0f/256.0f)) };
                        *(short4v*)&Ps[cur][off] = pk;
                    }
            }
            __syncthreads();                   // barrier per tile
        }
    } else {
        // ============ consumer: agg += P(jt-1) x V  (UNCHANGED R8) ============
        const int wv = w - 4;                  // n-strip selector 0..3
        f32x4 agg[16];                         // 64 AGPRs
        #pragma unroll
        for (int i = 0; i < 16; ++i) agg[i] = f32x4{0.f, 0.f, 0.f, 0.f};

        __syncthreads();                       // barrier 0 (matches producer)

        for (int jt = 0; jt <= T; ++jt) {
            if (jt >= 1) {
                const int p = (jt - 1) & 1;
                const int j0 = (jbase + jt - 1) * 64;
                #pragma unroll
                for (int ks = 0; ks < 2; ++ks) {
                    bf16x8 pf[4], vfr[4];
                    #pragma unroll
                    for (int nt = 0; nt < 4; ++nt) {
                        int n = wv * 64 + nt * 16 + lr;
                        vfr[nt] = *(const bf16x8*)(Xt + (size_t)n * 8192 + j0 + (ks * 4 + q) * 8);
                    }
                    #pragma unroll
                    for (int mt = 0; mt < 4; ++mt) {
                        int row = mt * 16 + lr;
                        pf[mt] = *(const bf16x8*)&Ps[p][row * 64 + (((ks*4 + q) ^ (row & 7)) << 3)];
                    }
                    #pragma unroll
                    for (int nt = 0; nt < 4; ++nt)
                        #pragma unroll
                        for (int mt = 0; mt < 4; ++mt)
                            agg[mt * 4 + nt] = __builtin_amdgcn_mfma_f32_16x16x32_bf16(
                                pf[mt], vfr[nt], agg[mt * 4 + nt], 0, 0, 0);
                }
            }
            __syncthreads();                   // barrier per tile
        }

        const int colbase = 256 + (sim * gridDim.z + jz) * 256;
        #pragma unroll
        for (int mt = 0; mt < 4; ++mt)
            #pragma unroll
            for (int nt = 0; nt < 4; ++nt)
                #pragma unroll
                for (int r = 0; r < 4; ++r) {
                    int m = m0 + mt * 16 + q * 4 + r;
                    int n = wv * 64 + nt * 16 + lr;
                    h[(size_t)m * ldh + colbase + n] = f2bf(agg[mt * 4 + nt][r]);
                }
    }
}

// ---------------------------------------------------------------- launch
extern "C" void kernel_launch(void* const* d_in, const int* in_sizes, int n_in,
                              void* d_out, int out_size, void* d_ws, size_t ws_size,
                              hipStream_t stream)
{
    const float* edge_x = (const float*)d_in[0];
    const float* W1 = (const float*)d_in[1];
    const float* b1 = (const float*)d_in[2];
    const float* W2 = (const float*)d_in[3];
    const float* b2 = (const float*)d_in[4];
    const float* Wo = (const float*)d_in[5];
    const float* bo = (const float*)d_in[6];

    const size_t fixed = 4194304u * 3 + 131072u * 2 + 4194304u; // Xt+e1+e2+Wt12+e8s
    const size_t need2 = (size_t)8192*1280*2 + fixed + (size_t)1280*256*2;
    const int js = (ws_size >= need2) ? 2 : 1;
    const int H = 256 + 2 * js * 256;              // 1280 or 768

    char* ws = (char*)d_ws;
    short* h    = (short*)ws;
    short* Xt   = (short*)(ws + (size_t)8192 * H * 2);
    short* e1   = (short*)((char*)Xt + 4194304);
    short* e2   = (short*)((char*)e1 + 4194304);
    short* Wt1  = (short*)((char*)e2 + 4194304);
    short* Wt2  = (short*)((char*)Wt1 + 131072);
    short* Wto  = (short*)((char*)Wt2 + 131072);
    char*  e1f8 = (char*)Wto + (size_t)H * 256 * 2;
    char*  e2f8 = e1f8 + 2097152;

    prep_all<<<dim3(256, 8), dim3(32, 8), 0, stream>>>(
        edge_x, h, H, Xt, W1, W2, Wo, Wt1, Wt2, Wto, H, js);

    // e1 and e2 GEMMs in one dispatch (grid.z)
    gemm_bias_relu<<<dim3(128, 4, 2), 256, 0, stream>>>(
        h, H, Wt1, Wt2, 256, b1, b2, e1, e2, 1, 256, 1);
    // fp8 shadow of e1/e2
    e_to_fp8<<<dim3(2048), 256, 0, stream>>>(e1, e2, e1f8, e2f8);
    // 64-row j-tiles: (8192/64)/js per split
    fused_simagg<<<dim3(128, 2, js), 512, 0, stream>>>(e1f8, e2f8, Xt, h, H, 128 / js);
    gemm_bias_relu<<<dim3(128, 4, 1), 256, 0, stream>>>(
        h, H, Wto, Wto, H, bo, bo, (float*)d_out, (float*)d_out, 0, 256, 0);
}